// Round 2
// baseline (370.711 us; speedup 1.0000x reference)
//
#include <hip/hip_runtime.h>

// RowAttentionWithPairBias  (B=1, M=128, N=256, C_IN=256, C_PAIR=128, H=8, C=32)
// Harness contract (established r0-r3): inputs fp32, OUTPUT fp32 (bf16-level
// tolerance). Internal compute: bf16 MFMA, fp32 accumulation.
// R4: k_qkvg/k_final use m97-style staged GEMM core: global_load_lds width=16,
// XOR-swizzled LDS ([row][chunk^(row&7)]) -> ds_read_b128 conflict-free (2-way).
// R5: exp2-space softmax (q pre-scaled by log2e), deferred normalization,
// transposed gate gT[m][o][i], no barriers in k_attn (P wave-private).
// R6 (this round):
//   - k_attn: merged iblk into the block (grid 128x8 = 1024 blocks = full
//     co-residency at 4 blocks/CU). Wave does 4 slabs of 16 q-rows; K/V
//     fragment loads repeat per slab -> L1-resident after slab 0.
//     #pragma unroll 1 + asm pointer barrier stop the compiler hoisting
//     128 VGPRs of loop-invariant K/V loads (would halve occupancy).
//   - bias: reverted R5's MFMA-C fold (it serialized load->mfma chains, +20us);
//     now a post-MFMA batch of 16 independent f32x4 loads + vector adds.
//   - gate prefetched at slab top; rcp for 1/sum.
//   - k_ln2bias: i-grouped block remap so biasT writes land 4-per-line.
// Verified fragment layouts (learn_hip m89/m91/m92/m120), v_mfma_f32_16x16x32_bf16:
//   A: lane holds A[m=lane&15][k=(lane>>4)*8 + j], j=0..7
//   B: lane holds B[k=(lane>>4)*8 + j][n=lane&15]
//   C/D: col = lane&15, row = (lane>>4)*4 + reg

typedef unsigned short u16;
typedef unsigned int   u32;
typedef __attribute__((ext_vector_type(8))) __bf16 bf16x8;
typedef __attribute__((ext_vector_type(4))) float  f32x4;
typedef __attribute__((ext_vector_type(4))) u16    u16x4;

#define DEV __device__ __forceinline__

#define LOG2E 1.4426950408889634f

DEV float bf2f(u16 s) {
    u32 u = ((u32)s) << 16;
    float f;
    __builtin_memcpy(&f, &u, 4);
    return f;
}
DEV u16 f2bf(float f) {
    __bf16 h = (__bf16)f;              // native RNE convert (m240: don't hand-roll)
    u16 u;
    __builtin_memcpy(&u, &h, 2);
    return u;
}

// async global->LDS, 16 B per lane; LDS dest wave-uniform base + lane*16
#define GLD_LDS16(gp, lp)                                                           \
    __builtin_amdgcn_global_load_lds(                                               \
        (const __attribute__((address_space(1))) u32*)(const void*)(gp),            \
        (__attribute__((address_space(3))) u32*)(void*)(lp), 16, 0, 0)

// ---------------------------------------------------------------- transpose W (fp32 -> bf16)
// WT[1024][256]: rows 0-255 Wq^T, 256-511 Wk^T, 512-767 Wv^T, 768-1023 Wgate^T
// WfT[256][256] = Wfinal^T
__global__ void k_transpose(const float* __restrict__ Wq, const float* __restrict__ Wk,
                            const float* __restrict__ Wv, const float* __restrict__ Wg,
                            const float* __restrict__ Wf,
                            u16* __restrict__ WT, u16* __restrict__ WfT) {
    int idx = blockIdx.x * 256 + threadIdx.x;
    if (idx < 1024 * 256) {
        int gcol = idx >> 8, p = idx & 255;
        int sel = gcol >> 8, c = gcol & 255;
        const float* W = sel == 0 ? Wq : sel == 1 ? Wk : sel == 2 ? Wv : Wg;
        WT[idx] = f2bf(W[p * 256 + c]);
    } else {
        int j = idx - 1024 * 256;            // [0, 65536)
        int d = j >> 8, hc = j & 255;
        WfT[j] = f2bf(Wf[hc * 256 + d]);
    }
}

// ---------------------------------------------------------------- LayerNorm 1
// x1d [32768][256] fp32 -> x1 [32768][256] bf16.  One wave per row.
__global__ __launch_bounds__(256) void k_ln1(const float* __restrict__ x,
                                             const float* __restrict__ gg,
                                             const float* __restrict__ bb,
                                             u16* __restrict__ y) {
    int lane = threadIdx.x & 63, wave = threadIdx.x >> 6;
    int row = blockIdx.x * 4 + wave;
    float4 xv = *(const float4*)(x + row * 256 + lane * 4);
    float v0 = xv.x, v1 = xv.y, v2 = xv.z, v3 = xv.w;
    float s  = v0 + v1 + v2 + v3;
    float s2 = v0*v0 + v1*v1 + v2*v2 + v3*v3;
    #pragma unroll
    for (int msk = 32; msk; msk >>= 1) {
        s  += __shfl_xor(s,  msk, 64);
        s2 += __shfl_xor(s2, msk, 64);
    }
    float mu  = s * (1.0f / 256.0f);
    float var = s2 * (1.0f / 256.0f) - mu * mu;
    float rs  = rsqrtf(var + 1e-5f);
    float4 gv = *(const float4*)(gg + lane * 4);
    float4 bv = *(const float4*)(bb + lane * 4);
    ushort4 o;
    o.x = f2bf((v0 - mu) * rs * gv.x + bv.x);
    o.y = f2bf((v1 - mu) * rs * gv.y + bv.y);
    o.z = f2bf((v2 - mu) * rs * gv.z + bv.z);
    o.w = f2bf((v3 - mu) * rs * gv.w + bv.w);
    *(ushort4*)(y + row * 256 + lane * 4) = o;
}

// ---------------------------------------------------------------- LN2 + pair bias
// x2d [65536][128] fp32 -> biasT[h][j][i] fp32, PRE-SCALED by log2e
// (biasT[h*65536 + j*256 + i]; transposed so k_attn loads float4 over i)
// Block remap groups 4 consecutive i at fixed j so lane-0 scatter writes
// share cache lines (wave-level read coalescing is unaffected).
__global__ __launch_bounds__(256) void k_ln2bias(const float* __restrict__ x2,
                                                 const float* __restrict__ gg,
                                                 const float* __restrict__ bb,
                                                 const float* __restrict__ W2d,
                                                 float* __restrict__ biasT) {
    int lane = threadIdx.x & 63, wave = threadIdx.x >> 6;
    int b = blockIdx.x;
    int i = (b >> 8) * 4 + wave;                     // [0,256)
    int j = b & 255;                                 // [0,256)
    int row = i * 256 + j;
    float2 xv = *(const float2*)(x2 + row * 128 + lane * 2);
    float v0 = xv.x, v1 = xv.y;
    float s = v0 + v1, s2 = v0*v0 + v1*v1;
    #pragma unroll
    for (int msk = 32; msk; msk >>= 1) {
        s  += __shfl_xor(s,  msk, 64);
        s2 += __shfl_xor(s2, msk, 64);
    }
    float mu  = s * (1.0f / 128.0f);
    float var = s2 * (1.0f / 128.0f) - mu * mu;
    float rs  = rsqrtf(var + 1e-5f);
    float2 gv = *(const float2*)(gg + lane * 2);
    float2 bv = *(const float2*)(bb + lane * 2);
    float xn0 = (v0 - mu) * rs * gv.x + bv.x;
    float xn1 = (v1 - mu) * rs * gv.y + bv.y;
    int p0 = lane * 2;
    float4 w0a = *(const float4*)(W2d + p0 * 8);
    float4 w0b = *(const float4*)(W2d + p0 * 8 + 4);
    float4 w1a = *(const float4*)(W2d + (p0 + 1) * 8);
    float4 w1b = *(const float4*)(W2d + (p0 + 1) * 8 + 4);
    float p[8];
    p[0] = xn0 * w0a.x + xn1 * w1a.x;
    p[1] = xn0 * w0a.y + xn1 * w1a.y;
    p[2] = xn0 * w0a.z + xn1 * w1a.z;
    p[3] = xn0 * w0a.w + xn1 * w1a.w;
    p[4] = xn0 * w0b.x + xn1 * w1b.x;
    p[5] = xn0 * w0b.y + xn1 * w1b.y;
    p[6] = xn0 * w0b.z + xn1 * w1b.z;
    p[7] = xn0 * w0b.w + xn1 * w1b.w;
    #pragma unroll
    for (int hh = 0; hh < 8; hh++)
        #pragma unroll
        for (int msk = 32; msk; msk >>= 1)
            p[hh] += __shfl_xor(p[hh], msk, 64);
    if (lane == 0) {
        #pragma unroll
        for (int hh = 0; hh < 8; hh++)
            biasT[hh * 65536 + j * 256 + i] = p[hh] * LOG2E;
    }
}

// ---------------------------------------------------------------- staged 128x128 GEMM core
// C[128x128 tile] = X[rowbase..+127][0..K) * WTb[colbase..+127][0..K)^T
// As/Bs: [128][64] u16, chunk-swizzled: phys chunk p of row r holds logical
// chunk p ^ (r&7)  (chunk = 8 u16 = 16 B).  BK=64, 2-barrier K-loop.
DEV void gemm128_core(const u16* __restrict__ X, const u16* __restrict__ WTb,
                      int rowbase, int colbase, int K,
                      u16* As, u16* Bs, f32x4 acc[4][4], int lane, int wave) {
    int l8 = lane & 7, r8 = lane >> 3;       // chunk-in-row, row-in-segment (8 rows/instr)
    int gchunk = l8 ^ (r8 & 7);              // xor swizzle: phys chunk l8 <- logical chunk l8^r8
    int lrow = lane & 15, quad = lane >> 4;
    int wr = (wave >> 1) * 64, wc = (wave & 1) * 64;

    for (int kk = 0; kk < K; kk += 64) {
        #pragma unroll
        for (int i = 0; i < 4; i++) {
            int s = wave * 4 + i;                            // segment 0..15 (8 rows each)
            const u16* g = X + (rowbase + s * 8 + r8) * K + kk + gchunk * 8;
            GLD_LDS16(g, As + s * 512);
        }
        #pragma unroll
        for (int i = 0; i < 4; i++) {
            int s = wave * 4 + i;
            const u16* g = WTb + (colbase + s * 8 + r8) * K + kk + gchunk * 8;
            GLD_LDS16(g, Bs + s * 512);
        }
        __syncthreads();                                     // waits vmcnt(0) for the DMA
        #pragma unroll
        for (int k2 = 0; k2 < 64; k2 += 32) {
            int cidx = (k2 >> 3) + quad;                     // logical chunk 0..7
            bf16x8 af[4], bf[4];
            #pragma unroll
            for (int t = 0; t < 4; t++) {
                int R = wr + t * 16 + lrow;
                af[t] = *(const bf16x8*)(As + R * 64 + ((cidx ^ (R & 7)) << 3));
            }
            #pragma unroll
            for (int t = 0; t < 4; t++) {
                int R = wc + t * 16 + lrow;
                bf[t] = *(const bf16x8*)(Bs + R * 64 + ((cidx ^ (R & 7)) << 3));
            }
            #pragma unroll
            for (int i = 0; i < 4; i++)
                #pragma unroll
                for (int j = 0; j < 4; j++)
                    acc[i][j] = __builtin_amdgcn_mfma_f32_16x16x32_bf16(af[i], bf[j], acc[i][j], 0, 0, 0);
        }
        __syncthreads();
    }
}

// ---------------------------------------------------------------- QKVG projection
// X=x1 [32768][256] @ WT -> cols 0-255 q (scaled by log2e/sqrt(C)), 256-511 k,
// 512-767 v (stored transposed vt[m][o][i]), 768-1023 gate (sigmoid applied,
// stored transposed gT[m][o][i]).
// grid (256, 8), block 256.  Block tile 128x128, wave tile 64x64.
__global__ __launch_bounds__(256) void k_qkvg(const u16* __restrict__ X, const u16* __restrict__ WT,
                                              u16* __restrict__ q, u16* __restrict__ kb,
                                              u16* __restrict__ vt, u16* __restrict__ gt,
                                              const float* __restrict__ bgate) {
    __shared__ u16 As[128 * 64];
    __shared__ u16 Bs[128 * 64];
    int lane = threadIdx.x & 63, wave = threadIdx.x >> 6;
    int rowbase = blockIdx.x * 128;
    int colbase = blockIdx.y * 128;
    f32x4 acc[4][4];
    #pragma unroll
    for (int i = 0; i < 4; i++)
        #pragma unroll
        for (int j = 0; j < 4; j++)
            acc[i][j] = (f32x4){0.f, 0.f, 0.f, 0.f};
    gemm128_core(X, WT, rowbase, colbase, 256, As, Bs, acc, lane, wave);
    int lrow = lane & 15, quad = lane >> 4;
    int wrb = rowbase + (wave >> 1) * 64, wcb = colbase + (wave & 1) * 64;
    int which = blockIdx.y >> 1;          // uniform per block: 0=q 1=k 2=v 3=gate
    #pragma unroll
    for (int it = 0; it < 4; it++)
        #pragma unroll
        for (int jt = 0; jt < 4; jt++)
            #pragma unroll
            for (int r = 0; r < 4; r++) {
                int grow = wrb + it * 16 + quad * 4 + r;
                int gcol = wcb + jt * 16 + lrow;
                int o = gcol & 255;
                float v = acc[it][jt][r];
                if (which == 0) {
                    // 1/sqrt(32) * log2(e): softmax runs in exp2 space
                    q[grow * 256 + o] = f2bf(v * (0.17677669529663687f * LOG2E));
                } else if (which == 1) {
                    kb[grow * 256 + o] = f2bf(v);
                } else if (which == 2) {
                    int mm = grow >> 8, ii = grow & 255;
                    vt[(mm * 256 + o) * 256 + ii] = f2bf(v);
                } else {
                    int mm = grow >> 8, ii = grow & 255;
                    float z = v + bgate[o];
                    gt[(mm * 256 + o) * 256 + ii] = f2bf(1.0f / (1.0f + __expf(-z)));
                }
            }
}

// ---------------------------------------------------------------- attention
// grid (m=128, h=8), block 256 (4 waves).  1024 blocks = 4/CU = fully
// co-resident.  Each wave processes 4 slabs of 16 q-rows (i0 = s*64+wave*16);
// K/V fragment loads repeat across slabs -> L1-resident after slab 0.
// No barriers: P is wave-private.
__global__ __launch_bounds__(256) void k_attn(const u16* __restrict__ q, const u16* __restrict__ kb,
                                              const u16* __restrict__ vt, const u16* __restrict__ gt,
                                              const float* __restrict__ biasT,
                                              u16* __restrict__ tmp) {
    __shared__ u16 P[4][16][264];          // +8 pad
    int lane = threadIdx.x & 63, wave = threadIdx.x >> 6;
    int lrow = lane & 15, quad = lane >> 4, lk = quad * 8;
    int m = blockIdx.x, h = blockIdx.y;
    const u16* qm  = q  + m * 65536 + h * 32;
    const u16* kbm = kb + m * 65536 + h * 32;
    const u16* vtm = vt + (m * 256 + h * 32) * 256;
    const u16* gtm = gt + (m * 256 + h * 32) * 256;
    u16*       tm  = tmp + m * 65536 + h * 32;
    const float* bh = biasT + h * 65536;
    const u16* Pw = &P[wave][0][0];

    #pragma unroll 1
    for (int s = 0; s < 4; s++) {
        // stop LICM/CSE from hoisting 128 VGPRs of loop-invariant K/V loads
        asm volatile("" : "+s"(kbm), "+s"(vtm));
        int i0 = s * 64 + wave * 16;

        // gate prefetch (independent of everything below)
        u16x4 gv4[2];
        #pragma unroll
        for (int ct = 0; ct < 2; ct++)
            gv4[ct] = *(const u16x4*)(gtm + (ct * 16 + lrow) * 256 + i0 + quad * 4);

        // ---- QK^T (zero C operand; K frags L1-hit for s>0)
        bf16x8 aq = *(const bf16x8*)(qm + (i0 + lrow) * 256 + lk);
        f32x4 acc[16];
        #pragma unroll
        for (int jt = 0; jt < 16; jt++) {
            bf16x8 bk = *(const bf16x8*)(kbm + (jt * 16 + lrow) * 256 + lk);
            f32x4 z = {0.f, 0.f, 0.f, 0.f};
            acc[jt] = __builtin_amdgcn_mfma_f32_16x16x32_bf16(aq, bk, z, 0, 0, 0);
        }

        // ---- bias add: 16 independent f32x4 loads (post-MFMA, off critical path)
        const float* bptr = bh + lrow * 256 + i0 + quad * 4;
        #pragma unroll
        for (int jt = 0; jt < 16; jt++) {
            f32x4 bfrag = *(const f32x4*)(bptr + jt * 4096);
            acc[jt] += bfrag;
        }

        // ---- softmax over j (log2 space): max, e = 2^(s-max), deferred 1/sum
        float rmax[4] = {-1e30f, -1e30f, -1e30f, -1e30f};
        #pragma unroll
        for (int jt = 0; jt < 16; jt++)
            #pragma unroll
            for (int r = 0; r < 4; r++)
                rmax[r] = fmaxf(rmax[r], acc[jt][r]);
        #pragma unroll
        for (int r = 0; r < 4; r++)
            #pragma unroll
            for (int msk = 8; msk; msk >>= 1)
                rmax[r] = fmaxf(rmax[r], __shfl_xor(rmax[r], msk, 64));
        float rsum[4] = {0.f, 0.f, 0.f, 0.f};
        #pragma unroll
        for (int jt = 0; jt < 16; jt++)
            #pragma unroll
            for (int r = 0; r < 4; r++) {
                float e = exp2f(acc[jt][r] - rmax[r]);        // raw v_exp_f32
                rsum[r] += e;
                P[wave][quad * 4 + r][jt * 16 + lrow] = f2bf(e);   // UNNORMALIZED
            }
        #pragma unroll
        for (int r = 0; r < 4; r++) {
            #pragma unroll
            for (int msk = 8; msk; msk >>= 1)
                rsum[r] += __shfl_xor(rsum[r], msk, 64);
            rsum[r] = __builtin_amdgcn_rcpf(rsum[r]);         // sum >= 1 always
        }

        // ---- PV : out[16 i][32 c], K=256 over j  (V frags L1-hit for s>0)
        f32x4 oacc[2] = {{0.f,0.f,0.f,0.f}, {0.f,0.f,0.f,0.f}};
        #pragma unroll
        for (int kk2 = 0; kk2 < 256; kk2 += 32) {
            bf16x8 ap = *(const bf16x8*)(Pw + lrow * 264 + kk2 + lk);
            #pragma unroll
            for (int ct = 0; ct < 2; ct++) {
                bf16x8 bv = *(const bf16x8*)(vtm + (ct * 16 + lrow) * 256 + kk2 + lk);
                oacc[ct] = __builtin_amdgcn_mfma_f32_16x16x32_bf16(ap, bv, oacc[ct], 0, 0, 0);
            }
        }

        // ---- 1/sum + gate multiply + store gated output [m,i,h,c]
        #pragma unroll
        for (int ct = 0; ct < 2; ct++)
            #pragma unroll
            for (int r = 0; r < 4; r++) {
                int i = i0 + quad * 4 + r;
                float gv = bf2f(gv4[ct][r]);
                tm[i * 256 + ct * 16 + lrow] = f2bf(oacc[ct][r] * rsum[r] * gv);
            }
    }
}

// ---------------------------------------------------------------- final projection
// tmp [32768][256] @ WfT + bfinal -> out FP32.  grid (256, 2).
__global__ __launch_bounds__(256) void k_final(const u16* __restrict__ T, const u16* __restrict__ WfT,
                                               const float* __restrict__ bfinal, float* __restrict__ out) {
    __shared__ u16 As[128 * 64];
    __shared__ u16 Bs[128 * 64];
    int lane = threadIdx.x & 63, wave = threadIdx.x >> 6;
    int rowbase = blockIdx.x * 128;
    int colbase = blockIdx.y * 128;
    f32x4 acc[4][4];
    #pragma unroll
    for (int i = 0; i < 4; i++)
        #pragma unroll
        for (int j = 0; j < 4; j++)
            acc[i][j] = (f32x4){0.f, 0.f, 0.f, 0.f};
    gemm128_core(T, WfT, rowbase, colbase, 256, As, Bs, acc, lane, wave);
    int lrow = lane & 15, quad = lane >> 4;
    int wrb = rowbase + (wave >> 1) * 64, wcb = colbase + (wave & 1) * 64;
    #pragma unroll
    for (int it = 0; it < 4; it++)
        #pragma unroll
        for (int jt = 0; jt < 4; jt++)
            #pragma unroll
            for (int r = 0; r < 4; r++) {
                int grow = wrb + it * 16 + quad * 4 + r;
                int gcol = wcb + jt * 16 + lrow;
                out[grow * 256 + gcol] = acc[it][jt][r] + bfinal[gcol];
            }
}

// ---------------------------------------------------------------- launch
extern "C" void kernel_launch(void* const* d_in, const int* in_sizes, int n_in,
                              void* d_out, int out_size, void* d_ws, size_t ws_size,
                              hipStream_t stream) {
    const float* x1d   = (const float*)d_in[0];
    const float* x2d   = (const float*)d_in[1];
    const float* ln1_g = (const float*)d_in[2];
    const float* ln1_b = (const float*)d_in[3];
    const float* ln2_g = (const float*)d_in[4];
    const float* ln2_b = (const float*)d_in[5];
    const float* Wq    = (const float*)d_in[6];
    const float* Wk    = (const float*)d_in[7];
    const float* Wv    = (const float*)d_in[8];
    const float* W2d   = (const float*)d_in[9];
    const float* Wg    = (const float*)d_in[10];
    const float* bg    = (const float*)d_in[11];
    const float* Wf    = (const float*)d_in[12];
    const float* bfin  = (const float*)d_in[13];
    float* out = (float*)d_out;

    char* ws = (char*)d_ws;
    u16*   x1   = (u16*)(ws);                    // 16,777,216 B  (reused as tmp)
    u16*   WT   = (u16*)(ws + 16777216);         //    524,288 B
    u16*   WfT  = (u16*)(ws + 17301504);         //    131,072 B
    float* bias = (float*)(ws + 17432576);       //  2,097,152 B  (biasT[h][j][i], log2e-scaled)
    u16*   qb   = (u16*)(ws + 19529728);         // 16,777,216 B
    u16*   kb   = (u16*)(ws + 36306944);         // 16,777,216 B
    u16*   vtb  = (u16*)(ws + 53084160);         // 16,777,216 B
    u16*   gb   = (u16*)(ws + 69861376);         // 16,777,216 B  (end: 86,638,592)
    u16*   tmp  = x1;                            // x1 dead after k_qkvg

    k_transpose<<<1280, 256, 0, stream>>>(Wq, Wk, Wv, Wg, Wf, WT, WfT);
    k_ln1<<<8192, 256, 0, stream>>>(x1d, ln1_g, ln1_b, x1);
    k_ln2bias<<<16384, 256, 0, stream>>>(x2d, ln2_g, ln2_b, W2d, bias);
    k_qkvg<<<dim3(256, 8), 256, 0, stream>>>(x1, WT, qb, kb, vtb, gb, bg);
    k_attn<<<dim3(128, 8), 256, 0, stream>>>(qb, kb, vtb, gb, bias, tmp);
    k_final<<<dim3(256, 2), 256, 0, stream>>>(tmp, WfT, bfin, out);
}

// Round 3
// 314.385 us; speedup vs baseline: 1.1792x; 1.1792x over previous
//
#include <hip/hip_runtime.h>

// RowAttentionWithPairBias  (B=1, M=128, N=256, C_IN=256, C_PAIR=128, H=8, C=32)
// Harness contract (established r0-r3): inputs fp32, OUTPUT fp32 (bf16-level
// tolerance). Internal compute: bf16 MFMA, fp32 accumulation.
// R4: k_qkvg/k_final use m97-style staged GEMM core: global_load_lds width=16,
// XOR-swizzled LDS ([row][chunk^(row&7)]) -> ds_read_b128 conflict-free (2-way).
// R5: exp2-space softmax (q pre-scaled by log2e), deferred normalization,
// transposed gate gT[m][o][i], no barriers in k_attn (P wave-private).
// R6: slab-merged k_attn REGRESSED (132us) -> reverted to R4 grid (128,8,4).
// R7 (this round):
//   - k_attn: NO-max softmax (inputs LN-bounded: |acc*log2e| <= ~12 << 127,
//     exp2 safe) -> removes 64 fmax + 64 sub + serial 16-shuffle max-reduce.
//   - row sum via all-ones MFMA B-operand (D[i][n] = sum_k P[i][k] in every
//     column) -> removes the 16-shuffle sum-reduce; softmax now ZERO shuffles.
//   - bias: float4 batch add post-MFMA (independent loads, off operand path).
//   - k_qkvg: v/gate epilogue stores packed as ushort4 (r=0..3 consecutive ii)
//     -> 4x fewer store instrs, 32B contiguous segments instead of 2B scatter.
// Verified fragment layouts (learn_hip m89/m91/m92/m120), v_mfma_f32_16x16x32_bf16:
//   A: lane holds A[m=lane&15][k=(lane>>4)*8 + j], j=0..7
//   B: lane holds B[k=(lane>>4)*8 + j][n=lane&15]
//   C/D: col = lane&15, row = (lane>>4)*4 + reg

typedef unsigned short u16;
typedef unsigned int   u32;
typedef __attribute__((ext_vector_type(8))) __bf16 bf16x8;
typedef __attribute__((ext_vector_type(4))) float  f32x4;
typedef __attribute__((ext_vector_type(4))) u16    u16x4;

#define DEV __device__ __forceinline__

#define LOG2E 1.4426950408889634f

DEV float bf2f(u16 s) {
    u32 u = ((u32)s) << 16;
    float f;
    __builtin_memcpy(&f, &u, 4);
    return f;
}
DEV u16 f2bf(float f) {
    __bf16 h = (__bf16)f;              // native RNE convert (m240: don't hand-roll)
    u16 u;
    __builtin_memcpy(&u, &h, 2);
    return u;
}

// async global->LDS, 16 B per lane; LDS dest wave-uniform base + lane*16
#define GLD_LDS16(gp, lp)                                                           \
    __builtin_amdgcn_global_load_lds(                                               \
        (const __attribute__((address_space(1))) u32*)(const void*)(gp),            \
        (__attribute__((address_space(3))) u32*)(void*)(lp), 16, 0, 0)

// ---------------------------------------------------------------- transpose W (fp32 -> bf16)
// WT[1024][256]: rows 0-255 Wq^T, 256-511 Wk^T, 512-767 Wv^T, 768-1023 Wgate^T
// WfT[256][256] = Wfinal^T
__global__ void k_transpose(const float* __restrict__ Wq, const float* __restrict__ Wk,
                            const float* __restrict__ Wv, const float* __restrict__ Wg,
                            const float* __restrict__ Wf,
                            u16* __restrict__ WT, u16* __restrict__ WfT) {
    int idx = blockIdx.x * 256 + threadIdx.x;
    if (idx < 1024 * 256) {
        int gcol = idx >> 8, p = idx & 255;
        int sel = gcol >> 8, c = gcol & 255;
        const float* W = sel == 0 ? Wq : sel == 1 ? Wk : sel == 2 ? Wv : Wg;
        WT[idx] = f2bf(W[p * 256 + c]);
    } else {
        int j = idx - 1024 * 256;            // [0, 65536)
        int d = j >> 8, hc = j & 255;
        WfT[j] = f2bf(Wf[hc * 256 + d]);
    }
}

// ---------------------------------------------------------------- LayerNorm 1
// x1d [32768][256] fp32 -> x1 [32768][256] bf16.  One wave per row.
__global__ __launch_bounds__(256) void k_ln1(const float* __restrict__ x,
                                             const float* __restrict__ gg,
                                             const float* __restrict__ bb,
                                             u16* __restrict__ y) {
    int lane = threadIdx.x & 63, wave = threadIdx.x >> 6;
    int row = blockIdx.x * 4 + wave;
    float4 xv = *(const float4*)(x + row * 256 + lane * 4);
    float v0 = xv.x, v1 = xv.y, v2 = xv.z, v3 = xv.w;
    float s  = v0 + v1 + v2 + v3;
    float s2 = v0*v0 + v1*v1 + v2*v2 + v3*v3;
    #pragma unroll
    for (int msk = 32; msk; msk >>= 1) {
        s  += __shfl_xor(s,  msk, 64);
        s2 += __shfl_xor(s2, msk, 64);
    }
    float mu  = s * (1.0f / 256.0f);
    float var = s2 * (1.0f / 256.0f) - mu * mu;
    float rs  = rsqrtf(var + 1e-5f);
    float4 gv = *(const float4*)(gg + lane * 4);
    float4 bv = *(const float4*)(bb + lane * 4);
    ushort4 o;
    o.x = f2bf((v0 - mu) * rs * gv.x + bv.x);
    o.y = f2bf((v1 - mu) * rs * gv.y + bv.y);
    o.z = f2bf((v2 - mu) * rs * gv.z + bv.z);
    o.w = f2bf((v3 - mu) * rs * gv.w + bv.w);
    *(ushort4*)(y + row * 256 + lane * 4) = o;
}

// ---------------------------------------------------------------- LN2 + pair bias
// x2d [65536][128] fp32 -> biasT[h][j][i] fp32, PRE-SCALED by log2e
// (biasT[h*65536 + j*256 + i]; transposed so k_attn loads float4 over i)
// Block remap groups 4 consecutive i at fixed j so lane-0 scatter writes
// share cache lines (wave-level read coalescing is unaffected).
__global__ __launch_bounds__(256) void k_ln2bias(const float* __restrict__ x2,
                                                 const float* __restrict__ gg,
                                                 const float* __restrict__ bb,
                                                 const float* __restrict__ W2d,
                                                 float* __restrict__ biasT) {
    int lane = threadIdx.x & 63, wave = threadIdx.x >> 6;
    int b = blockIdx.x;
    int i = (b >> 8) * 4 + wave;                     // [0,256)
    int j = b & 255;                                 // [0,256)
    int row = i * 256 + j;
    float2 xv = *(const float2*)(x2 + row * 128 + lane * 2);
    float v0 = xv.x, v1 = xv.y;
    float s = v0 + v1, s2 = v0*v0 + v1*v1;
    #pragma unroll
    for (int msk = 32; msk; msk >>= 1) {
        s  += __shfl_xor(s,  msk, 64);
        s2 += __shfl_xor(s2, msk, 64);
    }
    float mu  = s * (1.0f / 128.0f);
    float var = s2 * (1.0f / 128.0f) - mu * mu;
    float rs  = rsqrtf(var + 1e-5f);
    float2 gv = *(const float2*)(gg + lane * 2);
    float2 bv = *(const float2*)(bb + lane * 2);
    float xn0 = (v0 - mu) * rs * gv.x + bv.x;
    float xn1 = (v1 - mu) * rs * gv.y + bv.y;
    int p0 = lane * 2;
    float4 w0a = *(const float4*)(W2d + p0 * 8);
    float4 w0b = *(const float4*)(W2d + p0 * 8 + 4);
    float4 w1a = *(const float4*)(W2d + (p0 + 1) * 8);
    float4 w1b = *(const float4*)(W2d + (p0 + 1) * 8 + 4);
    float p[8];
    p[0] = xn0 * w0a.x + xn1 * w1a.x;
    p[1] = xn0 * w0a.y + xn1 * w1a.y;
    p[2] = xn0 * w0a.z + xn1 * w1a.z;
    p[3] = xn0 * w0a.w + xn1 * w1a.w;
    p[4] = xn0 * w0b.x + xn1 * w1b.x;
    p[5] = xn0 * w0b.y + xn1 * w1b.y;
    p[6] = xn0 * w0b.z + xn1 * w1b.z;
    p[7] = xn0 * w0b.w + xn1 * w1b.w;
    #pragma unroll
    for (int hh = 0; hh < 8; hh++)
        #pragma unroll
        for (int msk = 32; msk; msk >>= 1)
            p[hh] += __shfl_xor(p[hh], msk, 64);
    if (lane == 0) {
        #pragma unroll
        for (int hh = 0; hh < 8; hh++)
            biasT[hh * 65536 + j * 256 + i] = p[hh] * LOG2E;
    }
}

// ---------------------------------------------------------------- staged 128x128 GEMM core
// C[128x128 tile] = X[rowbase..+127][0..K) * WTb[colbase..+127][0..K)^T
// As/Bs: [128][64] u16, chunk-swizzled: phys chunk p of row r holds logical
// chunk p ^ (r&7)  (chunk = 8 u16 = 16 B).  BK=64, 2-barrier K-loop.
DEV void gemm128_core(const u16* __restrict__ X, const u16* __restrict__ WTb,
                      int rowbase, int colbase, int K,
                      u16* As, u16* Bs, f32x4 acc[4][4], int lane, int wave) {
    int l8 = lane & 7, r8 = lane >> 3;       // chunk-in-row, row-in-segment (8 rows/instr)
    int gchunk = l8 ^ (r8 & 7);              // xor swizzle: phys chunk l8 <- logical chunk l8^r8
    int lrow = lane & 15, quad = lane >> 4;
    int wr = (wave >> 1) * 64, wc = (wave & 1) * 64;

    for (int kk = 0; kk < K; kk += 64) {
        #pragma unroll
        for (int i = 0; i < 4; i++) {
            int s = wave * 4 + i;                            // segment 0..15 (8 rows each)
            const u16* g = X + (rowbase + s * 8 + r8) * K + kk + gchunk * 8;
            GLD_LDS16(g, As + s * 512);
        }
        #pragma unroll
        for (int i = 0; i < 4; i++) {
            int s = wave * 4 + i;
            const u16* g = WTb + (colbase + s * 8 + r8) * K + kk + gchunk * 8;
            GLD_LDS16(g, Bs + s * 512);
        }
        __syncthreads();                                     // waits vmcnt(0) for the DMA
        #pragma unroll
        for (int k2 = 0; k2 < 64; k2 += 32) {
            int cidx = (k2 >> 3) + quad;                     // logical chunk 0..7
            bf16x8 af[4], bf[4];
            #pragma unroll
            for (int t = 0; t < 4; t++) {
                int R = wr + t * 16 + lrow;
                af[t] = *(const bf16x8*)(As + R * 64 + ((cidx ^ (R & 7)) << 3));
            }
            #pragma unroll
            for (int t = 0; t < 4; t++) {
                int R = wc + t * 16 + lrow;
                bf[t] = *(const bf16x8*)(Bs + R * 64 + ((cidx ^ (R & 7)) << 3));
            }
            #pragma unroll
            for (int i = 0; i < 4; i++)
                #pragma unroll
                for (int j = 0; j < 4; j++)
                    acc[i][j] = __builtin_amdgcn_mfma_f32_16x16x32_bf16(af[i], bf[j], acc[i][j], 0, 0, 0);
        }
        __syncthreads();
    }
}

// ---------------------------------------------------------------- QKVG projection
// X=x1 [32768][256] @ WT -> cols 0-255 q (scaled by log2e/sqrt(C)), 256-511 k,
// 512-767 v (stored transposed vt[m][o][i]), 768-1023 gate (sigmoid applied,
// stored transposed gT[m][o][i]).
// grid (256, 8), block 256.  Block tile 128x128, wave tile 64x64.
// v/gate stores: r=0..3 are consecutive ii in the transposed layout -> pack
// into one ushort4 store (16 stores/lane, 32B contiguous segments).
__global__ __launch_bounds__(256) void k_qkvg(const u16* __restrict__ X, const u16* __restrict__ WT,
                                              u16* __restrict__ q, u16* __restrict__ kb,
                                              u16* __restrict__ vt, u16* __restrict__ gt,
                                              const float* __restrict__ bgate) {
    __shared__ u16 As[128 * 64];
    __shared__ u16 Bs[128 * 64];
    int lane = threadIdx.x & 63, wave = threadIdx.x >> 6;
    int rowbase = blockIdx.x * 128;
    int colbase = blockIdx.y * 128;
    f32x4 acc[4][4];
    #pragma unroll
    for (int i = 0; i < 4; i++)
        #pragma unroll
        for (int j = 0; j < 4; j++)
            acc[i][j] = (f32x4){0.f, 0.f, 0.f, 0.f};
    gemm128_core(X, WT, rowbase, colbase, 256, As, Bs, acc, lane, wave);
    int lrow = lane & 15, quad = lane >> 4;
    int wrb = rowbase + (wave >> 1) * 64, wcb = colbase + (wave & 1) * 64;
    int which = blockIdx.y >> 1;          // uniform per block: 0=q 1=k 2=v 3=gate
    #pragma unroll
    for (int it = 0; it < 4; it++)
        #pragma unroll
        for (int jt = 0; jt < 4; jt++) {
            int grow0 = wrb + it * 16 + quad * 4;      // +r stays in same 256-row band
            int gcol  = wcb + jt * 16 + lrow;
            int o = gcol & 255;
            if (which == 0) {
                #pragma unroll
                for (int r = 0; r < 4; r++)
                    q[(grow0 + r) * 256 + o] = f2bf(acc[it][jt][r] * (0.17677669529663687f * LOG2E));
            } else if (which == 1) {
                #pragma unroll
                for (int r = 0; r < 4; r++)
                    kb[(grow0 + r) * 256 + o] = f2bf(acc[it][jt][r]);
            } else if (which == 2) {
                int mm = grow0 >> 8, ii = grow0 & 255;
                ushort4 pv;
                pv.x = f2bf(acc[it][jt][0]);
                pv.y = f2bf(acc[it][jt][1]);
                pv.z = f2bf(acc[it][jt][2]);
                pv.w = f2bf(acc[it][jt][3]);
                *(ushort4*)(vt + (mm * 256 + o) * 256 + ii) = pv;
            } else {
                int mm = grow0 >> 8, ii = grow0 & 255;
                float bgo = bgate[o];
                ushort4 pv;
                pv.x = f2bf(1.0f / (1.0f + __expf(-(acc[it][jt][0] + bgo))));
                pv.y = f2bf(1.0f / (1.0f + __expf(-(acc[it][jt][1] + bgo))));
                pv.z = f2bf(1.0f / (1.0f + __expf(-(acc[it][jt][2] + bgo))));
                pv.w = f2bf(1.0f / (1.0f + __expf(-(acc[it][jt][3] + bgo))));
                *(ushort4*)(gt + (mm * 256 + o) * 256 + ii) = pv;
            }
        }
}

// ---------------------------------------------------------------- attention
// grid (m=128, h=8, iblk=4), block 256 (4 waves, 16 q-rows each).
// Zero-shuffle softmax: no max subtraction (LN-bounded scores, exp2 safe),
// row sum via all-ones MFMA B-operand (every lane gets its rows' sums).
// No barriers: P is wave-private.
__global__ __launch_bounds__(256) void k_attn(const u16* __restrict__ q, const u16* __restrict__ kb,
                                              const u16* __restrict__ vt, const u16* __restrict__ gt,
                                              const float* __restrict__ biasT,
                                              u16* __restrict__ tmp) {
    __shared__ u16 P[4][16][264];          // +8 pad
    int lane = threadIdx.x & 63, wave = threadIdx.x >> 6;
    int lrow = lane & 15, quad = lane >> 4, lk = quad * 8;
    int m = blockIdx.x, h = blockIdx.y, iblk = blockIdx.z;
    int i0 = iblk * 64 + wave * 16;

    const u16* qm  = q  + m * 65536 + h * 32;
    const u16* kbm = kb + m * 65536 + h * 32;
    const u16* vtm = vt + (m * 256 + h * 32) * 256;
    const u16* gtm = gt + (m * 256 + h * 32) * 256;
    u16*       tm  = tmp + m * 65536 + h * 32;

    // gate prefetch (independent of everything below)
    u16x4 gv4[2];
    #pragma unroll
    for (int ct = 0; ct < 2; ct++)
        gv4[ct] = *(const u16x4*)(gtm + (ct * 16 + lrow) * 256 + i0 + quad * 4);

    // ---- QK^T (zero C operand)
    bf16x8 aq = *(const bf16x8*)(qm + (i0 + lrow) * 256 + lk);
    f32x4 acc[16];
    #pragma unroll
    for (int jt = 0; jt < 16; jt++) {
        bf16x8 bk = *(const bf16x8*)(kbm + (jt * 16 + lrow) * 256 + lk);
        f32x4 z = {0.f, 0.f, 0.f, 0.f};
        acc[jt] = __builtin_amdgcn_mfma_f32_16x16x32_bf16(aq, bk, z, 0, 0, 0);
    }

    // ---- bias add: 16 independent f32x4 loads (post-MFMA, off operand path)
    const float* bptr = biasT + h * 65536 + lrow * 256 + i0 + quad * 4;
    #pragma unroll
    for (int jt = 0; jt < 16; jt++) {
        f32x4 bfrag = *(const f32x4*)(bptr + jt * 4096);
        acc[jt] += bfrag;
    }

    // ---- exp2 + P write.  NO max subtraction: |acc| <= ~12 (LN-bounded),
    // exp2f range-safe; P unnormalized bf16 (floating -> same rel. precision).
    #pragma unroll
    for (int jt = 0; jt < 16; jt++)
        #pragma unroll
        for (int r = 0; r < 4; r++)
            P[wave][quad * 4 + r][jt * 16 + lrow] = f2bf(exp2f(acc[jt][r]));

    // ---- PV + ones-sum : out[16 i][32 c], K=256 over j (P wave-private)
    bf16x8 ones;
    {
        u16 ou = 0x3F80;                   // bf16 1.0
        __bf16 ob;
        __builtin_memcpy(&ob, &ou, 2);
        #pragma unroll
        for (int j = 0; j < 8; j++) ones[j] = ob;
    }
    f32x4 oacc[2] = {{0.f,0.f,0.f,0.f}, {0.f,0.f,0.f,0.f}};
    f32x4 osum = {0.f, 0.f, 0.f, 0.f};
    const u16* Pw = &P[wave][0][0];
    #pragma unroll
    for (int kk2 = 0; kk2 < 256; kk2 += 32) {
        bf16x8 ap = *(const bf16x8*)(Pw + lrow * 264 + kk2 + lk);
        osum = __builtin_amdgcn_mfma_f32_16x16x32_bf16(ap, ones, osum, 0, 0, 0);
        #pragma unroll
        for (int ct = 0; ct < 2; ct++) {
            bf16x8 bv = *(const bf16x8*)(vtm + (ct * 16 + lrow) * 256 + kk2 + lk);
            oacc[ct] = __builtin_amdgcn_mfma_f32_16x16x32_bf16(ap, bv, oacc[ct], 0, 0, 0);
        }
    }

    // ---- 1/sum + gate multiply + store gated output [m,i,h,c]
    float rinv[4];
    #pragma unroll
    for (int r = 0; r < 4; r++)
        rinv[r] = __builtin_amdgcn_rcpf(osum[r]);
    #pragma unroll
    for (int ct = 0; ct < 2; ct++)
        #pragma unroll
        for (int r = 0; r < 4; r++) {
            int i = i0 + quad * 4 + r;
            float gv = bf2f(gv4[ct][r]);
            tm[i * 256 + ct * 16 + lrow] = f2bf(oacc[ct][r] * rinv[r] * gv);
        }
}

// ---------------------------------------------------------------- final projection
// tmp [32768][256] @ WfT + bfinal -> out FP32.  grid (256, 2).
__global__ __launch_bounds__(256) void k_final(const u16* __restrict__ T, const u16* __restrict__ WfT,
                                               const float* __restrict__ bfinal, float* __restrict__ out) {
    __shared__ u16 As[128 * 64];
    __shared__ u16 Bs[128 * 64];
    int lane = threadIdx.x & 63, wave = threadIdx.x >> 6;
    int rowbase = blockIdx.x * 128;
    int colbase = blockIdx.y * 128;
    f32x4 acc[4][4];
    #pragma unroll
    for (int i = 0; i < 4; i++)
        #pragma unroll
        for (int j = 0; j < 4; j++)
            acc[i][j] = (f32x4){0.f, 0.f, 0.f, 0.f};
    gemm128_core(T, WfT, rowbase, colbase, 256, As, Bs, acc, lane, wave);
    int lrow = lane & 15, quad = lane >> 4;
    int wrb = rowbase + (wave >> 1) * 64, wcb = colbase + (wave & 1) * 64;
    #pragma unroll
    for (int it = 0; it < 4; it++)
        #pragma unroll
        for (int jt = 0; jt < 4; jt++)
            #pragma unroll
            for (int r = 0; r < 4; r++) {
                int grow = wrb + it * 16 + quad * 4 + r;
                int gcol = wcb + jt * 16 + lrow;
                out[grow * 256 + gcol] = acc[it][jt][r] + bfinal[gcol];
            }
}

// ---------------------------------------------------------------- launch
extern "C" void kernel_launch(void* const* d_in, const int* in_sizes, int n_in,
                              void* d_out, int out_size, void* d_ws, size_t ws_size,
                              hipStream_t stream) {
    const float* x1d   = (const float*)d_in[0];
    const float* x2d   = (const float*)d_in[1];
    const float* ln1_g = (const float*)d_in[2];
    const float* ln1_b = (const float*)d_in[3];
    const float* ln2_g = (const float*)d_in[4];
    const float* ln2_b = (const float*)d_in[5];
    const float* Wq    = (const float*)d_in[6];
    const float* Wk    = (const float*)d_in[7];
    const float* Wv    = (const float*)d_in[8];
    const float* W2d   = (const float*)d_in[9];
    const float* Wg    = (const float*)d_in[10];
    const float* bg    = (const float*)d_in[11];
    const float* Wf    = (const float*)d_in[12];
    const float* bfin  = (const float*)d_in[13];
    float* out = (float*)d_out;

    char* ws = (char*)d_ws;
    u16*   x1   = (u16*)(ws);                    // 16,777,216 B  (reused as tmp)
    u16*   WT   = (u16*)(ws + 16777216);         //    524,288 B
    u16*   WfT  = (u16*)(ws + 17301504);         //    131,072 B
    float* bias = (float*)(ws + 17432576);       //  2,097,152 B  (biasT[h][j][i], log2e-scaled)
    u16*   qb   = (u16*)(ws + 19529728);         // 16,777,216 B
    u16*   kb   = (u16*)(ws + 36306944);         // 16,777,216 B
    u16*   vtb  = (u16*)(ws + 53084160);         // 16,777,216 B
    u16*   gb   = (u16*)(ws + 69861376);         // 16,777,216 B  (end: 86,638,592)
    u16*   tmp  = x1;                            // x1 dead after k_qkvg

    k_transpose<<<1280, 256, 0, stream>>>(Wq, Wk, Wv, Wg, Wf, WT, WfT);
    k_ln1<<<8192, 256, 0, stream>>>(x1d, ln1_g, ln1_b, x1);
    k_ln2bias<<<16384, 256, 0, stream>>>(x2d, ln2_g, ln2_b, W2d, bias);
    k_qkvg<<<dim3(256, 8), 256, 0, stream>>>(x1, WT, qb, kb, vtb, gb, bg);
    k_attn<<<dim3(128, 8, 4), 256, 0, stream>>>(qb, kb, vtb, gb, bias, tmp);
    k_final<<<dim3(256, 2), 256, 0, stream>>>(tmp, WfT, bfin, out);
}

// Round 4
// 261.071 us; speedup vs baseline: 1.4200x; 1.2042x over previous
//
#include <hip/hip_runtime.h>

// RowAttentionWithPairBias  (B=1, M=128, N=256, C_IN=256, C_PAIR=128, H=8, C=32)
// Harness contract (established r0-r3): inputs fp32, OUTPUT fp32 (bf16-level
// tolerance). Internal compute: bf16 MFMA, fp32 accumulation.
// R4: k_qkvg/k_final use m97-style staged GEMM core: global_load_lds width=16,
// XOR-swizzled LDS ([row][chunk^(row&7)]) -> ds_read_b128 conflict-free (2-way).
// R5: exp2-space softmax (q pre-scaled by log2e), deferred normalization,
// transposed gate gT[m][o][i], no barriers in k_attn (P wave-private).
// R6: slab-merged k_attn REGRESSED (132us; serial HBM chains) -> reverted.
// R7: zero-shuffle softmax (no-max exp2 + ones-MFMA row sum) - VALU down but
// dur flat: k_attn is LATENCY-bound (~4 loads in flight, 900cyc HBM).
// R8 (this round): DMA-staged k_attn.
//   - K[256j][32c] + V[32o][256i] slices staged to LDS once per block via
//     global_load_lds (32 bulk DMA instrs replace 128 latency-chained loads;
//     shared by all 4 waves). Inverse-swizzled global src, XOR-swizzled reads.
//   - P swizzled [16][256] (no pad): V+K+P = exactly 64KB LDS, 2 blocks/CU.
//   - grid (128,8,2); each wave does 2 slabs of 16 q-rows from LDS.
//   - remaining HBM ops/wave-slab: 1 q + 16 bias + 2 gate + 8 stores.
// Verified fragment layouts (learn_hip m89/m91/m92/m120), v_mfma_f32_16x16x32_bf16:
//   A: lane holds A[m=lane&15][k=(lane>>4)*8 + j], j=0..7
//   B: lane holds B[k=(lane>>4)*8 + j][n=lane&15]
//   C/D: col = lane&15, row = (lane>>4)*4 + reg

typedef unsigned short u16;
typedef unsigned int   u32;
typedef __attribute__((ext_vector_type(8))) __bf16 bf16x8;
typedef __attribute__((ext_vector_type(4))) float  f32x4;
typedef __attribute__((ext_vector_type(4))) u16    u16x4;

#define DEV __device__ __forceinline__

#define LOG2E 1.4426950408889634f

DEV float bf2f(u16 s) {
    u32 u = ((u32)s) << 16;
    float f;
    __builtin_memcpy(&f, &u, 4);
    return f;
}
DEV u16 f2bf(float f) {
    __bf16 h = (__bf16)f;              // native RNE convert (m240: don't hand-roll)
    u16 u;
    __builtin_memcpy(&u, &h, 2);
    return u;
}

// async global->LDS, 16 B per lane; LDS dest wave-uniform base + lane*16
#define GLD_LDS16(gp, lp)                                                           \
    __builtin_amdgcn_global_load_lds(                                               \
        (const __attribute__((address_space(1))) u32*)(const void*)(gp),            \
        (__attribute__((address_space(3))) u32*)(void*)(lp), 16, 0, 0)

// ---------------------------------------------------------------- transpose W (fp32 -> bf16)
// WT[1024][256]: rows 0-255 Wq^T, 256-511 Wk^T, 512-767 Wv^T, 768-1023 Wgate^T
// WfT[256][256] = Wfinal^T
__global__ void k_transpose(const float* __restrict__ Wq, const float* __restrict__ Wk,
                            const float* __restrict__ Wv, const float* __restrict__ Wg,
                            const float* __restrict__ Wf,
                            u16* __restrict__ WT, u16* __restrict__ WfT) {
    int idx = blockIdx.x * 256 + threadIdx.x;
    if (idx < 1024 * 256) {
        int gcol = idx >> 8, p = idx & 255;
        int sel = gcol >> 8, c = gcol & 255;
        const float* W = sel == 0 ? Wq : sel == 1 ? Wk : sel == 2 ? Wv : Wg;
        WT[idx] = f2bf(W[p * 256 + c]);
    } else {
        int j = idx - 1024 * 256;            // [0, 65536)
        int d = j >> 8, hc = j & 255;
        WfT[j] = f2bf(Wf[hc * 256 + d]);
    }
}

// ---------------------------------------------------------------- LayerNorm 1
// x1d [32768][256] fp32 -> x1 [32768][256] bf16.  One wave per row.
__global__ __launch_bounds__(256) void k_ln1(const float* __restrict__ x,
                                             const float* __restrict__ gg,
                                             const float* __restrict__ bb,
                                             u16* __restrict__ y) {
    int lane = threadIdx.x & 63, wave = threadIdx.x >> 6;
    int row = blockIdx.x * 4 + wave;
    float4 xv = *(const float4*)(x + row * 256 + lane * 4);
    float v0 = xv.x, v1 = xv.y, v2 = xv.z, v3 = xv.w;
    float s  = v0 + v1 + v2 + v3;
    float s2 = v0*v0 + v1*v1 + v2*v2 + v3*v3;
    #pragma unroll
    for (int msk = 32; msk; msk >>= 1) {
        s  += __shfl_xor(s,  msk, 64);
        s2 += __shfl_xor(s2, msk, 64);
    }
    float mu  = s * (1.0f / 256.0f);
    float var = s2 * (1.0f / 256.0f) - mu * mu;
    float rs  = rsqrtf(var + 1e-5f);
    float4 gv = *(const float4*)(gg + lane * 4);
    float4 bv = *(const float4*)(bb + lane * 4);
    ushort4 o;
    o.x = f2bf((v0 - mu) * rs * gv.x + bv.x);
    o.y = f2bf((v1 - mu) * rs * gv.y + bv.y);
    o.z = f2bf((v2 - mu) * rs * gv.z + bv.z);
    o.w = f2bf((v3 - mu) * rs * gv.w + bv.w);
    *(ushort4*)(y + row * 256 + lane * 4) = o;
}

// ---------------------------------------------------------------- LN2 + pair bias
// x2d [65536][128] fp32 -> biasT[h][j][i] fp32, PRE-SCALED by log2e
// (biasT[h*65536 + j*256 + i]; transposed so k_attn loads float4 over i)
__global__ __launch_bounds__(256) void k_ln2bias(const float* __restrict__ x2,
                                                 const float* __restrict__ gg,
                                                 const float* __restrict__ bb,
                                                 const float* __restrict__ W2d,
                                                 float* __restrict__ biasT) {
    int lane = threadIdx.x & 63, wave = threadIdx.x >> 6;
    int b = blockIdx.x;
    int i = (b >> 8) * 4 + wave;                     // [0,256)
    int j = b & 255;                                 // [0,256)
    int row = i * 256 + j;
    float2 xv = *(const float2*)(x2 + row * 128 + lane * 2);
    float v0 = xv.x, v1 = xv.y;
    float s = v0 + v1, s2 = v0*v0 + v1*v1;
    #pragma unroll
    for (int msk = 32; msk; msk >>= 1) {
        s  += __shfl_xor(s,  msk, 64);
        s2 += __shfl_xor(s2, msk, 64);
    }
    float mu  = s * (1.0f / 128.0f);
    float var = s2 * (1.0f / 128.0f) - mu * mu;
    float rs  = rsqrtf(var + 1e-5f);
    float2 gv = *(const float2*)(gg + lane * 2);
    float2 bv = *(const float2*)(bb + lane * 2);
    float xn0 = (v0 - mu) * rs * gv.x + bv.x;
    float xn1 = (v1 - mu) * rs * gv.y + bv.y;
    int p0 = lane * 2;
    float4 w0a = *(const float4*)(W2d + p0 * 8);
    float4 w0b = *(const float4*)(W2d + p0 * 8 + 4);
    float4 w1a = *(const float4*)(W2d + (p0 + 1) * 8);
    float4 w1b = *(const float4*)(W2d + (p0 + 1) * 8 + 4);
    float p[8];
    p[0] = xn0 * w0a.x + xn1 * w1a.x;
    p[1] = xn0 * w0a.y + xn1 * w1a.y;
    p[2] = xn0 * w0a.z + xn1 * w1a.z;
    p[3] = xn0 * w0a.w + xn1 * w1a.w;
    p[4] = xn0 * w0b.x + xn1 * w1b.x;
    p[5] = xn0 * w0b.y + xn1 * w1b.y;
    p[6] = xn0 * w0b.z + xn1 * w1b.z;
    p[7] = xn0 * w0b.w + xn1 * w1b.w;
    #pragma unroll
    for (int hh = 0; hh < 8; hh++)
        #pragma unroll
        for (int msk = 32; msk; msk >>= 1)
            p[hh] += __shfl_xor(p[hh], msk, 64);
    if (lane == 0) {
        #pragma unroll
        for (int hh = 0; hh < 8; hh++)
            biasT[hh * 65536 + j * 256 + i] = p[hh] * LOG2E;
    }
}

// ---------------------------------------------------------------- staged 128x128 GEMM core
// C[128x128 tile] = X[rowbase..+127][0..K) * WTb[colbase..+127][0..K)^T
// As/Bs: [128][64] u16, chunk-swizzled: phys chunk p of row r holds logical
// chunk p ^ (r&7)  (chunk = 8 u16 = 16 B).  BK=64, 2-barrier K-loop.
DEV void gemm128_core(const u16* __restrict__ X, const u16* __restrict__ WTb,
                      int rowbase, int colbase, int K,
                      u16* As, u16* Bs, f32x4 acc[4][4], int lane, int wave) {
    int l8 = lane & 7, r8 = lane >> 3;       // chunk-in-row, row-in-segment (8 rows/instr)
    int gchunk = l8 ^ (r8 & 7);              // xor swizzle: phys chunk l8 <- logical chunk l8^r8
    int lrow = lane & 15, quad = lane >> 4;
    int wr = (wave >> 1) * 64, wc = (wave & 1) * 64;

    for (int kk = 0; kk < K; kk += 64) {
        #pragma unroll
        for (int i = 0; i < 4; i++) {
            int s = wave * 4 + i;                            // segment 0..15 (8 rows each)
            const u16* g = X + (rowbase + s * 8 + r8) * K + kk + gchunk * 8;
            GLD_LDS16(g, As + s * 512);
        }
        #pragma unroll
        for (int i = 0; i < 4; i++) {
            int s = wave * 4 + i;
            const u16* g = WTb + (colbase + s * 8 + r8) * K + kk + gchunk * 8;
            GLD_LDS16(g, Bs + s * 512);
        }
        __syncthreads();                                     // waits vmcnt(0) for the DMA
        #pragma unroll
        for (int k2 = 0; k2 < 64; k2 += 32) {
            int cidx = (k2 >> 3) + quad;                     // logical chunk 0..7
            bf16x8 af[4], bf[4];
            #pragma unroll
            for (int t = 0; t < 4; t++) {
                int R = wr + t * 16 + lrow;
                af[t] = *(const bf16x8*)(As + R * 64 + ((cidx ^ (R & 7)) << 3));
            }
            #pragma unroll
            for (int t = 0; t < 4; t++) {
                int R = wc + t * 16 + lrow;
                bf[t] = *(const bf16x8*)(Bs + R * 64 + ((cidx ^ (R & 7)) << 3));
            }
            #pragma unroll
            for (int i = 0; i < 4; i++)
                #pragma unroll
                for (int j = 0; j < 4; j++)
                    acc[i][j] = __builtin_amdgcn_mfma_f32_16x16x32_bf16(af[i], bf[j], acc[i][j], 0, 0, 0);
        }
        __syncthreads();
    }
}

// ---------------------------------------------------------------- QKVG projection
// X=x1 [32768][256] @ WT -> cols 0-255 q (scaled by log2e/sqrt(C)), 256-511 k,
// 512-767 v (stored transposed vt[m][o][i]), 768-1023 gate (sigmoid applied,
// stored transposed gT[m][o][i]).
// grid (256, 8), block 256.  Block tile 128x128, wave tile 64x64.
__global__ __launch_bounds__(256) void k_qkvg(const u16* __restrict__ X, const u16* __restrict__ WT,
                                              u16* __restrict__ q, u16* __restrict__ kb,
                                              u16* __restrict__ vt, u16* __restrict__ gt,
                                              const float* __restrict__ bgate) {
    __shared__ u16 As[128 * 64];
    __shared__ u16 Bs[128 * 64];
    int lane = threadIdx.x & 63, wave = threadIdx.x >> 6;
    int rowbase = blockIdx.x * 128;
    int colbase = blockIdx.y * 128;
    f32x4 acc[4][4];
    #pragma unroll
    for (int i = 0; i < 4; i++)
        #pragma unroll
        for (int j = 0; j < 4; j++)
            acc[i][j] = (f32x4){0.f, 0.f, 0.f, 0.f};
    gemm128_core(X, WT, rowbase, colbase, 256, As, Bs, acc, lane, wave);
    int lrow = lane & 15, quad = lane >> 4;
    int wrb = rowbase + (wave >> 1) * 64, wcb = colbase + (wave & 1) * 64;
    int which = blockIdx.y >> 1;          // uniform per block: 0=q 1=k 2=v 3=gate
    #pragma unroll
    for (int it = 0; it < 4; it++)
        #pragma unroll
        for (int jt = 0; jt < 4; jt++) {
            int grow0 = wrb + it * 16 + quad * 4;      // +r stays in same 256-row band
            int gcol  = wcb + jt * 16 + lrow;
            int o = gcol & 255;
            if (which == 0) {
                #pragma unroll
                for (int r = 0; r < 4; r++)
                    q[(grow0 + r) * 256 + o] = f2bf(acc[it][jt][r] * (0.17677669529663687f * LOG2E));
            } else if (which == 1) {
                #pragma unroll
                for (int r = 0; r < 4; r++)
                    kb[(grow0 + r) * 256 + o] = f2bf(acc[it][jt][r]);
            } else if (which == 2) {
                int mm = grow0 >> 8, ii = grow0 & 255;
                ushort4 pv;
                pv.x = f2bf(acc[it][jt][0]);
                pv.y = f2bf(acc[it][jt][1]);
                pv.z = f2bf(acc[it][jt][2]);
                pv.w = f2bf(acc[it][jt][3]);
                *(ushort4*)(vt + (mm * 256 + o) * 256 + ii) = pv;
            } else {
                int mm = grow0 >> 8, ii = grow0 & 255;
                float bgo = bgate[o];
                ushort4 pv;
                pv.x = f2bf(1.0f / (1.0f + __expf(-(acc[it][jt][0] + bgo))));
                pv.y = f2bf(1.0f / (1.0f + __expf(-(acc[it][jt][1] + bgo))));
                pv.z = f2bf(1.0f / (1.0f + __expf(-(acc[it][jt][2] + bgo))));
                pv.w = f2bf(1.0f / (1.0f + __expf(-(acc[it][jt][3] + bgo))));
                *(ushort4*)(gt + (mm * 256 + o) * 256 + ii) = pv;
            }
        }
}

// ---------------------------------------------------------------- attention
// grid (m=128, h=8, iblk=2), block 256 (4 waves).  DMA-staged K/V in LDS.
// LDS map (u16 idx): V [0,8192) = [32 o][256 ii] swizzled
//                    K [8192,16384) = [256 j][32 c] pair-swizzled
//                    P [16384,32768) = per-wave [16][256] swizzled
// Swizzles (16B chunk XOR, all verified write<->read consistent):
//   K: addr = (j>>1)*128B + ((((j&1)*4+quad) ^ ((j>>1)&7)))*16B
//   V: addr = o*512B + ((ch ^ ((o&1)<<2)))*16B,  ch = 16B-chunk in row
//   P: addr = i*512B + (((j>>3) ^ ((i&1)<<2)))*16B + (j&7)*2B
// Each wave: 2 slabs of 16 q-rows; per slab HBM = 1 q + 16 bias + 2 gate + 8 st.
__global__ __launch_bounds__(256, 2) void k_attn(const u16* __restrict__ q, const u16* __restrict__ kb,
                                                 const u16* __restrict__ vt, const u16* __restrict__ gt,
                                                 const float* __restrict__ biasT,
                                                 u16* __restrict__ tmp) {
    __shared__ u16 S[32768];               // exactly 64 KiB
    u16* Vs = S;
    u16* Ks = S + 8192;
    int lane = threadIdx.x & 63, wave = threadIdx.x >> 6;
    int lrow = lane & 15, quad = lane >> 4, lk = quad * 8;
    int m = blockIdx.x, h = blockIdx.y, iblk = blockIdx.z;

    const u16* qm  = q  + m * 65536 + h * 32;
    const u16* kbm = kb + m * 65536 + h * 32;
    const u16* vtm = vt + (m * 256 + h * 32) * 256;
    const u16* gtm = gt + (m * 256 + h * 32) * 256;
    u16*       tm  = tmp + m * 65536 + h * 32;
    const float* bh = biasT + h * 65536;
    u16* Pw = S + 16384 + wave * 4096;

    // ---- bulk DMA stage: K segs by waves 0-1, V segs by waves 2-3 (8 each)
    if (wave < 2) {
        // inverse of K read swizzle: lane l of seg -> (j, c-chunk)
        int ch = (lane & 7) ^ ((lane >> 3) & 7);         // (j&1)*4 + quad
        int jrow = ((lane >> 3) << 1) + (ch >> 2);       // j within 16-row seg
        const u16* g0 = kbm + (ch & 3) * 8;
        #pragma unroll
        for (int t = 0; t < 8; t++) {
            int seg = wave * 8 + t;
            GLD_LDS16(g0 + (seg * 16 + jrow) * 256, Ks + seg * 512);
        }
    } else {
        // inverse of V read swizzle: lane l of seg -> (o, ii-chunk)
        int orow = lane >> 5;                            // o within 2-row seg
        int ch = (lane & 31) ^ ((orow & 1) << 2);
        const u16* g0 = vtm + ch * 8;
        #pragma unroll
        for (int t = 0; t < 8; t++) {
            int seg = (wave - 2) * 8 + t;
            GLD_LDS16(g0 + (seg * 2 + orow) * 256, Vs + seg * 512);
        }
    }
    __syncthreads();                                     // drains DMA (vmcnt 0)

    bf16x8 ones;
    {
        u16 ou = 0x3F80;                   // bf16 1.0
        __bf16 ob;
        __builtin_memcpy(&ob, &ou, 2);
        #pragma unroll
        for (int j = 0; j < 8; j++) ones[j] = ob;
    }

    #pragma unroll
    for (int s = 0; s < 2; s++) {
        int i0 = iblk * 128 + s * 64 + wave * 16;

        // gate prefetch (independent)
        u16x4 gv4[2];
        #pragma unroll
        for (int ct = 0; ct < 2; ct++)
            gv4[ct] = *(const u16x4*)(gtm + (ct * 16 + lrow) * 256 + i0 + quad * 4);

        // ---- QK^T from LDS K
        bf16x8 aq = *(const bf16x8*)(qm + (i0 + lrow) * 256 + lk);
        f32x4 acc[16];
        #pragma unroll
        for (int jt = 0; jt < 16; jt++) {
            int ra = (jt * 8 + (lrow >> 1)) * 64 +
                     (((((lrow & 1) << 2) | quad) ^ (lrow >> 1)) << 3);
            bf16x8 bk = *(const bf16x8*)(Ks + ra);
            f32x4 z = {0.f, 0.f, 0.f, 0.f};
            acc[jt] = __builtin_amdgcn_mfma_f32_16x16x32_bf16(aq, bk, z, 0, 0, 0);
        }

        // ---- bias add: 16 independent f32x4 loads
        const float* bptr = bh + lrow * 256 + i0 + quad * 4;
        #pragma unroll
        for (int jt = 0; jt < 16; jt++) {
            f32x4 bfrag = *(const f32x4*)(bptr + jt * 4096);
            acc[jt] += bfrag;
        }

        // ---- exp2 + swizzled P write (no max: LN-bounded, exp2-safe)
        #pragma unroll
        for (int jt = 0; jt < 16; jt++)
            #pragma unroll
            for (int r = 0; r < 4; r++) {
                int i = quad * 4 + r;
                int j = jt * 16 + lrow;
                Pw[i * 256 + (((j >> 3) ^ ((i & 1) << 2)) << 3) + (j & 7)] =
                    f2bf(exp2f(acc[jt][r]));
            }

        // ---- PV + ones-sum from LDS (P wave-private, V shared)
        f32x4 oacc[2] = {{0.f,0.f,0.f,0.f}, {0.f,0.f,0.f,0.f}};
        f32x4 osum = {0.f, 0.f, 0.f, 0.f};
        #pragma unroll
        for (int kk2 = 0; kk2 < 256; kk2 += 32) {
            int c0 = (kk2 >> 3) + quad;
            bf16x8 ap = *(const bf16x8*)(Pw + lrow * 256 + ((c0 ^ ((lrow & 1) << 2)) << 3));
            osum = __builtin_amdgcn_mfma_f32_16x16x32_bf16(ap, ones, osum, 0, 0, 0);
            #pragma unroll
            for (int ct = 0; ct < 2; ct++) {
                int o = ct * 16 + lrow;
                bf16x8 bv = *(const bf16x8*)(Vs + o * 256 + ((c0 ^ ((o & 1) << 2)) << 3));
                oacc[ct] = __builtin_amdgcn_mfma_f32_16x16x32_bf16(ap, bv, oacc[ct], 0, 0, 0);
            }
        }

        // ---- 1/sum + gate multiply + store gated output [m,i,h,c]
        float rinv[4];
        #pragma unroll
        for (int r = 0; r < 4; r++)
            rinv[r] = __builtin_amdgcn_rcpf(osum[r]);
        #pragma unroll
        for (int ct = 0; ct < 2; ct++)
            #pragma unroll
            for (int r = 0; r < 4; r++) {
                int i = i0 + quad * 4 + r;
                float gv = bf2f(gv4[ct][r]);
                tm[i * 256 + ct * 16 + lrow] = f2bf(oacc[ct][r] * rinv[r] * gv);
            }
    }
}

// ---------------------------------------------------------------- final projection
// tmp [32768][256] @ WfT + bfinal -> out FP32.  grid (256, 2).
__global__ __launch_bounds__(256) void k_final(const u16* __restrict__ T, const u16* __restrict__ WfT,
                                               const float* __restrict__ bfinal, float* __restrict__ out) {
    __shared__ u16 As[128 * 64];
    __shared__ u16 Bs[128 * 64];
    int lane = threadIdx.x & 63, wave = threadIdx.x >> 6;
    int rowbase = blockIdx.x * 128;
    int colbase = blockIdx.y * 128;
    f32x4 acc[4][4];
    #pragma unroll
    for (int i = 0; i < 4; i++)
        #pragma unroll
        for (int j = 0; j < 4; j++)
            acc[i][j] = (f32x4){0.f, 0.f, 0.f, 0.f};
    gemm128_core(T, WfT, rowbase, colbase, 256, As, Bs, acc, lane, wave);
    int lrow = lane & 15, quad = lane >> 4;
    int wrb = rowbase + (wave >> 1) * 64, wcb = colbase + (wave & 1) * 64;
    #pragma unroll
    for (int it = 0; it < 4; it++)
        #pragma unroll
        for (int jt = 0; jt < 4; jt++)
            #pragma unroll
            for (int r = 0; r < 4; r++) {
                int grow = wrb + it * 16 + quad * 4 + r;
                int gcol = wcb + jt * 16 + lrow;
                out[grow * 256 + gcol] = acc[it][jt][r] + bfinal[gcol];
            }
}

// ---------------------------------------------------------------- launch
extern "C" void kernel_launch(void* const* d_in, const int* in_sizes, int n_in,
                              void* d_out, int out_size, void* d_ws, size_t ws_size,
                              hipStream_t stream) {
    const float* x1d   = (const float*)d_in[0];
    const float* x2d   = (const float*)d_in[1];
    const float* ln1_g = (const float*)d_in[2];
    const float* ln1_b = (const float*)d_in[3];
    const float* ln2_g = (const float*)d_in[4];
    const float* ln2_b = (const float*)d_in[5];
    const float* Wq    = (const float*)d_in[6];
    const float* Wk    = (const float*)d_in[7];
    const float* Wv    = (const float*)d_in[8];
    const float* W2d   = (const float*)d_in[9];
    const float* Wg    = (const float*)d_in[10];
    const float* bg    = (const float*)d_in[11];
    const float* Wf    = (const float*)d_in[12];
    const float* bfin  = (const float*)d_in[13];
    float* out = (float*)d_out;

    char* ws = (char*)d_ws;
    u16*   x1   = (u16*)(ws);                    // 16,777,216 B  (reused as tmp)
    u16*   WT   = (u16*)(ws + 16777216);         //    524,288 B
    u16*   WfT  = (u16*)(ws + 17301504);         //    131,072 B
    float* bias = (float*)(ws + 17432576);       //  2,097,152 B  (biasT[h][j][i], log2e-scaled)
    u16*   qb   = (u16*)(ws + 19529728);         // 16,777,216 B
    u16*   kb   = (u16*)(ws + 36306944);         // 16,777,216 B
    u16*   vtb  = (u16*)(ws + 53084160);         // 16,777,216 B
    u16*   gb   = (u16*)(ws + 69861376);         // 16,777,216 B  (end: 86,638,592)
    u16*   tmp  = x1;                            // x1 dead after k_qkvg

    k_transpose<<<1280, 256, 0, stream>>>(Wq, Wk, Wv, Wg, Wf, WT, WfT);
    k_ln1<<<8192, 256, 0, stream>>>(x1d, ln1_g, ln1_b, x1);
    k_ln2bias<<<16384, 256, 0, stream>>>(x2d, ln2_g, ln2_b, W2d, bias);
    k_qkvg<<<dim3(256, 8), 256, 0, stream>>>(x1, WT, qb, kb, vtb, gb, bg);
    k_attn<<<dim3(128, 8, 2), 256, 0, stream>>>(qb, kb, vtb, gb, bias, tmp);
    k_final<<<dim3(256, 2), 256, 0, stream>>>(tmp, WfT, bfin, out);
}

// Round 5
// 258.427 us; speedup vs baseline: 1.4345x; 1.0102x over previous
//
#include <hip/hip_runtime.h>

// RowAttentionWithPairBias  (B=1, M=128, N=256, C_IN=256, C_PAIR=128, H=8, C=32)
// Harness contract (established r0-r3): inputs fp32, OUTPUT fp32 (bf16-level
// tolerance). Internal compute: bf16 MFMA, fp32 accumulation.
// R4: k_qkvg/k_final use m97-style staged GEMM core: global_load_lds width=16,
// XOR-swizzled LDS ([row][chunk^(row&7)]) -> ds_read_b128 conflict-free (2-way).
// R5: exp2-space softmax (q pre-scaled by log2e), deferred normalization,
// transposed gate gT[m][o][i], no barriers in k_attn (P wave-private).
// R6: slab-merged k_attn REGRESSED (132us; serial HBM chains) -> reverted.
// R7: zero-shuffle softmax (no-max exp2 + ones-MFMA row sum).
// R8: DMA-staged K/V in LDS: 108 -> 57us. BUT bank conflicts 0.5M -> 6.8M:
//     P/V swizzles XOR'd only 1 row bit -> 4-way conflicts (~10us).
// R9 (this round):
//   - K swizzle: phys chunk = quad ^ ((j>>1)&3)  (64B rows contribute 4
//     slots/row; 8-lane group covers all 8 bank-slots - enumerated).
//   - V swizzle: phys chunk = c ^ (o&7)  (full 3-bit row XOR; 512B rows).
//   - P: back to proven padded [16][264] (wave-private, no DMA constraint;
//     528B rows rotate bank base by 4/row -> reads conflict-free).
//   - iblk merged (grid 128x8): K/V staged ONCE per (m,h), 4 slabs/wave from
//     LDS (unlike R6, slabs have no HBM K/V chains). Staging traffic halves.
// Verified fragment layouts (learn_hip m89/m91/m92/m120), v_mfma_f32_16x16x32_bf16:
//   A: lane holds A[m=lane&15][k=(lane>>4)*8 + j], j=0..7
//   B: lane holds B[k=(lane>>4)*8 + j][n=lane&15]
//   C/D: col = lane&15, row = (lane>>4)*4 + reg

typedef unsigned short u16;
typedef unsigned int   u32;
typedef __attribute__((ext_vector_type(8))) __bf16 bf16x8;
typedef __attribute__((ext_vector_type(4))) float  f32x4;
typedef __attribute__((ext_vector_type(4))) u16    u16x4;

#define DEV __device__ __forceinline__

#define LOG2E 1.4426950408889634f

DEV float bf2f(u16 s) {
    u32 u = ((u32)s) << 16;
    float f;
    __builtin_memcpy(&f, &u, 4);
    return f;
}
DEV u16 f2bf(float f) {
    __bf16 h = (__bf16)f;              // native RNE convert (m240: don't hand-roll)
    u16 u;
    __builtin_memcpy(&u, &h, 2);
    return u;
}

// async global->LDS, 16 B per lane; LDS dest wave-uniform base + lane*16
#define GLD_LDS16(gp, lp)                                                           \
    __builtin_amdgcn_global_load_lds(                                               \
        (const __attribute__((address_space(1))) u32*)(const void*)(gp),            \
        (__attribute__((address_space(3))) u32*)(void*)(lp), 16, 0, 0)

// ---------------------------------------------------------------- transpose W (fp32 -> bf16)
// WT[1024][256]: rows 0-255 Wq^T, 256-511 Wk^T, 512-767 Wv^T, 768-1023 Wgate^T
// WfT[256][256] = Wfinal^T
__global__ void k_transpose(const float* __restrict__ Wq, const float* __restrict__ Wk,
                            const float* __restrict__ Wv, const float* __restrict__ Wg,
                            const float* __restrict__ Wf,
                            u16* __restrict__ WT, u16* __restrict__ WfT) {
    int idx = blockIdx.x * 256 + threadIdx.x;
    if (idx < 1024 * 256) {
        int gcol = idx >> 8, p = idx & 255;
        int sel = gcol >> 8, c = gcol & 255;
        const float* W = sel == 0 ? Wq : sel == 1 ? Wk : sel == 2 ? Wv : Wg;
        WT[idx] = f2bf(W[p * 256 + c]);
    } else {
        int j = idx - 1024 * 256;            // [0, 65536)
        int d = j >> 8, hc = j & 255;
        WfT[j] = f2bf(Wf[hc * 256 + d]);
    }
}

// ---------------------------------------------------------------- LayerNorm 1
// x1d [32768][256] fp32 -> x1 [32768][256] bf16.  One wave per row.
__global__ __launch_bounds__(256) void k_ln1(const float* __restrict__ x,
                                             const float* __restrict__ gg,
                                             const float* __restrict__ bb,
                                             u16* __restrict__ y) {
    int lane = threadIdx.x & 63, wave = threadIdx.x >> 6;
    int row = blockIdx.x * 4 + wave;
    float4 xv = *(const float4*)(x + row * 256 + lane * 4);
    float v0 = xv.x, v1 = xv.y, v2 = xv.z, v3 = xv.w;
    float s  = v0 + v1 + v2 + v3;
    float s2 = v0*v0 + v1*v1 + v2*v2 + v3*v3;
    #pragma unroll
    for (int msk = 32; msk; msk >>= 1) {
        s  += __shfl_xor(s,  msk, 64);
        s2 += __shfl_xor(s2, msk, 64);
    }
    float mu  = s * (1.0f / 256.0f);
    float var = s2 * (1.0f / 256.0f) - mu * mu;
    float rs  = rsqrtf(var + 1e-5f);
    float4 gv = *(const float4*)(gg + lane * 4);
    float4 bv = *(const float4*)(bb + lane * 4);
    ushort4 o;
    o.x = f2bf((v0 - mu) * rs * gv.x + bv.x);
    o.y = f2bf((v1 - mu) * rs * gv.y + bv.y);
    o.z = f2bf((v2 - mu) * rs * gv.z + bv.z);
    o.w = f2bf((v3 - mu) * rs * gv.w + bv.w);
    *(ushort4*)(y + row * 256 + lane * 4) = o;
}

// ---------------------------------------------------------------- LN2 + pair bias
// x2d [65536][128] fp32 -> biasT[h][j][i] fp32, PRE-SCALED by log2e
// (biasT[h*65536 + j*256 + i]; transposed so k_attn loads float4 over i)
__global__ __launch_bounds__(256) void k_ln2bias(const float* __restrict__ x2,
                                                 const float* __restrict__ gg,
                                                 const float* __restrict__ bb,
                                                 const float* __restrict__ W2d,
                                                 float* __restrict__ biasT) {
    int lane = threadIdx.x & 63, wave = threadIdx.x >> 6;
    int b = blockIdx.x;
    int i = (b >> 8) * 4 + wave;                     // [0,256)
    int j = b & 255;                                 // [0,256)
    int row = i * 256 + j;
    float2 xv = *(const float2*)(x2 + row * 128 + lane * 2);
    float v0 = xv.x, v1 = xv.y;
    float s = v0 + v1, s2 = v0*v0 + v1*v1;
    #pragma unroll
    for (int msk = 32; msk; msk >>= 1) {
        s  += __shfl_xor(s,  msk, 64);
        s2 += __shfl_xor(s2, msk, 64);
    }
    float mu  = s * (1.0f / 128.0f);
    float var = s2 * (1.0f / 128.0f) - mu * mu;
    float rs  = rsqrtf(var + 1e-5f);
    float2 gv = *(const float2*)(gg + lane * 2);
    float2 bv = *(const float2*)(bb + lane * 2);
    float xn0 = (v0 - mu) * rs * gv.x + bv.x;
    float xn1 = (v1 - mu) * rs * gv.y + bv.y;
    int p0 = lane * 2;
    float4 w0a = *(const float4*)(W2d + p0 * 8);
    float4 w0b = *(const float4*)(W2d + p0 * 8 + 4);
    float4 w1a = *(const float4*)(W2d + (p0 + 1) * 8);
    float4 w1b = *(const float4*)(W2d + (p0 + 1) * 8 + 4);
    float p[8];
    p[0] = xn0 * w0a.x + xn1 * w1a.x;
    p[1] = xn0 * w0a.y + xn1 * w1a.y;
    p[2] = xn0 * w0a.z + xn1 * w1a.z;
    p[3] = xn0 * w0a.w + xn1 * w1a.w;
    p[4] = xn0 * w0b.x + xn1 * w1b.x;
    p[5] = xn0 * w0b.y + xn1 * w1b.y;
    p[6] = xn0 * w0b.z + xn1 * w1b.z;
    p[7] = xn0 * w0b.w + xn1 * w1b.w;
    #pragma unroll
    for (int hh = 0; hh < 8; hh++)
        #pragma unroll
        for (int msk = 32; msk; msk >>= 1)
            p[hh] += __shfl_xor(p[hh], msk, 64);
    if (lane == 0) {
        #pragma unroll
        for (int hh = 0; hh < 8; hh++)
            biasT[hh * 65536 + j * 256 + i] = p[hh] * LOG2E;
    }
}

// ---------------------------------------------------------------- staged 128x128 GEMM core
// C[128x128 tile] = X[rowbase..+127][0..K) * WTb[colbase..+127][0..K)^T
// As/Bs: [128][64] u16, chunk-swizzled: phys chunk p of row r holds logical
// chunk p ^ (r&7)  (chunk = 8 u16 = 16 B).  BK=64, 2-barrier K-loop.
DEV void gemm128_core(const u16* __restrict__ X, const u16* __restrict__ WTb,
                      int rowbase, int colbase, int K,
                      u16* As, u16* Bs, f32x4 acc[4][4], int lane, int wave) {
    int l8 = lane & 7, r8 = lane >> 3;       // chunk-in-row, row-in-segment (8 rows/instr)
    int gchunk = l8 ^ (r8 & 7);              // xor swizzle: phys chunk l8 <- logical chunk l8^r8
    int lrow = lane & 15, quad = lane >> 4;
    int wr = (wave >> 1) * 64, wc = (wave & 1) * 64;

    for (int kk = 0; kk < K; kk += 64) {
        #pragma unroll
        for (int i = 0; i < 4; i++) {
            int s = wave * 4 + i;                            // segment 0..15 (8 rows each)
            const u16* g = X + (rowbase + s * 8 + r8) * K + kk + gchunk * 8;
            GLD_LDS16(g, As + s * 512);
        }
        #pragma unroll
        for (int i = 0; i < 4; i++) {
            int s = wave * 4 + i;
            const u16* g = WTb + (colbase + s * 8 + r8) * K + kk + gchunk * 8;
            GLD_LDS16(g, Bs + s * 512);
        }
        __syncthreads();                                     // waits vmcnt(0) for the DMA
        #pragma unroll
        for (int k2 = 0; k2 < 64; k2 += 32) {
            int cidx = (k2 >> 3) + quad;                     // logical chunk 0..7
            bf16x8 af[4], bf[4];
            #pragma unroll
            for (int t = 0; t < 4; t++) {
                int R = wr + t * 16 + lrow;
                af[t] = *(const bf16x8*)(As + R * 64 + ((cidx ^ (R & 7)) << 3));
            }
            #pragma unroll
            for (int t = 0; t < 4; t++) {
                int R = wc + t * 16 + lrow;
                bf[t] = *(const bf16x8*)(Bs + R * 64 + ((cidx ^ (R & 7)) << 3));
            }
            #pragma unroll
            for (int i = 0; i < 4; i++)
                #pragma unroll
                for (int j = 0; j < 4; j++)
                    acc[i][j] = __builtin_amdgcn_mfma_f32_16x16x32_bf16(af[i], bf[j], acc[i][j], 0, 0, 0);
        }
        __syncthreads();
    }
}

// ---------------------------------------------------------------- QKVG projection
// X=x1 [32768][256] @ WT -> cols 0-255 q (scaled by log2e/sqrt(C)), 256-511 k,
// 512-767 v (stored transposed vt[m][o][i]), 768-1023 gate (sigmoid applied,
// stored transposed gT[m][o][i]).
// grid (256, 8), block 256.  Block tile 128x128, wave tile 64x64.
__global__ __launch_bounds__(256) void k_qkvg(const u16* __restrict__ X, const u16* __restrict__ WT,
                                              u16* __restrict__ q, u16* __restrict__ kb,
                                              u16* __restrict__ vt, u16* __restrict__ gt,
                                              const float* __restrict__ bgate) {
    __shared__ u16 As[128 * 64];
    __shared__ u16 Bs[128 * 64];
    int lane = threadIdx.x & 63, wave = threadIdx.x >> 6;
    int rowbase = blockIdx.x * 128;
    int colbase = blockIdx.y * 128;
    f32x4 acc[4][4];
    #pragma unroll
    for (int i = 0; i < 4; i++)
        #pragma unroll
        for (int j = 0; j < 4; j++)
            acc[i][j] = (f32x4){0.f, 0.f, 0.f, 0.f};
    gemm128_core(X, WT, rowbase, colbase, 256, As, Bs, acc, lane, wave);
    int lrow = lane & 15, quad = lane >> 4;
    int wrb = rowbase + (wave >> 1) * 64, wcb = colbase + (wave & 1) * 64;
    int which = blockIdx.y >> 1;          // uniform per block: 0=q 1=k 2=v 3=gate
    #pragma unroll
    for (int it = 0; it < 4; it++)
        #pragma unroll
        for (int jt = 0; jt < 4; jt++) {
            int grow0 = wrb + it * 16 + quad * 4;      // +r stays in same 256-row band
            int gcol  = wcb + jt * 16 + lrow;
            int o = gcol & 255;
            if (which == 0) {
                #pragma unroll
                for (int r = 0; r < 4; r++)
                    q[(grow0 + r) * 256 + o] = f2bf(acc[it][jt][r] * (0.17677669529663687f * LOG2E));
            } else if (which == 1) {
                #pragma unroll
                for (int r = 0; r < 4; r++)
                    kb[(grow0 + r) * 256 + o] = f2bf(acc[it][jt][r]);
            } else if (which == 2) {
                int mm = grow0 >> 8, ii = grow0 & 255;
                ushort4 pv;
                pv.x = f2bf(acc[it][jt][0]);
                pv.y = f2bf(acc[it][jt][1]);
                pv.z = f2bf(acc[it][jt][2]);
                pv.w = f2bf(acc[it][jt][3]);
                *(ushort4*)(vt + (mm * 256 + o) * 256 + ii) = pv;
            } else {
                int mm = grow0 >> 8, ii = grow0 & 255;
                float bgo = bgate[o];
                ushort4 pv;
                pv.x = f2bf(1.0f / (1.0f + __expf(-(acc[it][jt][0] + bgo))));
                pv.y = f2bf(1.0f / (1.0f + __expf(-(acc[it][jt][1] + bgo))));
                pv.z = f2bf(1.0f / (1.0f + __expf(-(acc[it][jt][2] + bgo))));
                pv.w = f2bf(1.0f / (1.0f + __expf(-(acc[it][jt][3] + bgo))));
                *(ushort4*)(gt + (mm * 256 + o) * 256 + ii) = pv;
            }
        }
}

// ---------------------------------------------------------------- attention
// grid (m=128, h=8), block 256 (4 waves).  K/V staged ONCE per block; each
// wave does 4 slabs of 16 q-rows from LDS.
// LDS map (u16 idx):
//   Vs [0,8192):      V [32 o][256 ii], phys chunk = c ^ (o&7)        (c = ii>>3)
//   Ks [8192,16384):  K [256 j][32 cc], phys chunk = q ^ ((j>>1)&3)   (q = cc>>3)
//   P  [16384,33280): per-wave padded [16][264]  (proven R7 layout)
// Conflict model (8-lane service group, 16B slots):
//   K: slot%8 = 4j + chunk -> lanes 0-7 hit slots 0,4,1,5,2,6,3,7 (distinct)
//   V: 512B rows contribute 0; chunk = c0 ^ (o&7) distinct over 8 lanes
//   P: 528B rows rotate bank base by 4/row -> conflict-free reads, 2-way writes
__global__ __launch_bounds__(256, 2) void k_attn(const u16* __restrict__ q, const u16* __restrict__ kb,
                                                 const u16* __restrict__ vt, const u16* __restrict__ gt,
                                                 const float* __restrict__ biasT,
                                                 u16* __restrict__ tmp) {
    __shared__ u16 S[33280];               // 66560 B -> 2 blocks/CU
    u16* Vs = S;
    u16* Ks = S + 8192;
    int lane = threadIdx.x & 63, wave = threadIdx.x >> 6;
    int lrow = lane & 15, quad = lane >> 4, lk = quad * 8;
    int m = blockIdx.x, h = blockIdx.y;

    const u16* qm  = q  + m * 65536 + h * 32;
    const u16* kbm = kb + m * 65536 + h * 32;
    const u16* vtm = vt + (m * 256 + h * 32) * 256;
    const u16* gtm = gt + (m * 256 + h * 32) * 256;
    u16*       tm  = tmp + m * 65536 + h * 32;
    const float* bh = biasT + h * 65536;
    u16* Pw = S + 16384 + wave * 4224;     // [16][264]

    // ---- bulk DMA stage: K segs (16x 1KB) waves 0-1, V segs waves 2-3
    if (wave < 2) {
        // lane l -> LDS (j_local = l>>2, phys_q = l&3); logical q = phys ^ ((j>>1)&3)
        // with j = seg*16 + (l>>2): (j>>1)&3 = (l>>3)&3
        int jl = lane >> 2;
        int qq = (lane & 3) ^ ((lane >> 3) & 3);
        const u16* gK = kbm + jl * 256 + qq * 8;
        #pragma unroll
        for (int t = 0; t < 8; t++) {
            int seg = wave * 8 + t;
            GLD_LDS16(gK + seg * 4096, Ks + seg * 512);
        }
    } else {
        // lane l -> LDS (o_local = l>>5, phys = l&31); logical c = phys ^ (o&7)
        // with o = seg*2 + (l>>5): o&7 = (2*t + (l>>5))&7  ((wave-2)*16 == 0 mod 8)
        int ol = lane >> 5;
        #pragma unroll
        for (int t = 0; t < 8; t++) {
            int seg = (wave - 2) * 8 + t;
            int cc = (lane & 31) ^ ((2 * t + ol) & 7);
            const u16* gV = vtm + (seg * 2 + ol) * 256 + cc * 8;
            GLD_LDS16(gV, Vs + seg * 512);
        }
    }
    __syncthreads();                                     // drains DMA (vmcnt 0)

    bf16x8 ones;
    {
        u16 ou = 0x3F80;                   // bf16 1.0
        __bf16 ob;
        __builtin_memcpy(&ob, &ou, 2);
        #pragma unroll
        for (int j = 0; j < 8; j++) ones[j] = ob;
    }

    #pragma unroll
    for (int s = 0; s < 4; s++) {
        int i0 = s * 64 + wave * 16;

        // gate prefetch (independent)
        u16x4 gv4[2];
        #pragma unroll
        for (int ct = 0; ct < 2; ct++)
            gv4[ct] = *(const u16x4*)(gtm + (ct * 16 + lrow) * 256 + i0 + quad * 4);

        // ---- QK^T from LDS K  (swizzled: chunk = quad ^ ((lrow>>1)&3))
        bf16x8 aq = *(const bf16x8*)(qm + (i0 + lrow) * 256 + lk);
        f32x4 acc[16];
        #pragma unroll
        for (int jt = 0; jt < 16; jt++) {
            int ra = (jt * 16 + lrow) * 32 + ((quad ^ ((lrow >> 1) & 3)) << 3);
            bf16x8 bk = *(const bf16x8*)(Ks + ra);
            f32x4 z = {0.f, 0.f, 0.f, 0.f};
            acc[jt] = __builtin_amdgcn_mfma_f32_16x16x32_bf16(aq, bk, z, 0, 0, 0);
        }

        // ---- bias add: 16 independent f32x4 loads (post-MFMA, off operand path)
        const float* bptr = bh + lrow * 256 + i0 + quad * 4;
        #pragma unroll
        for (int jt = 0; jt < 16; jt++) {
            f32x4 bfrag = *(const f32x4*)(bptr + jt * 4096);
            acc[jt] += bfrag;
        }

        // ---- exp2 + P write (padded [16][264]; no max: LN-bounded, exp2-safe)
        #pragma unroll
        for (int jt = 0; jt < 16; jt++)
            #pragma unroll
            for (int r = 0; r < 4; r++)
                Pw[(quad * 4 + r) * 264 + jt * 16 + lrow] = f2bf(exp2f(acc[jt][r]));

        // ---- PV + ones-sum from LDS (P wave-private, V shared)
        f32x4 oacc[2] = {{0.f,0.f,0.f,0.f}, {0.f,0.f,0.f,0.f}};
        f32x4 osum = {0.f, 0.f, 0.f, 0.f};
        #pragma unroll
        for (int kk2 = 0; kk2 < 256; kk2 += 32) {
            int c0 = (kk2 >> 3) + quad;
            bf16x8 ap = *(const bf16x8*)(Pw + lrow * 264 + kk2 + lk);
            osum = __builtin_amdgcn_mfma_f32_16x16x32_bf16(ap, ones, osum, 0, 0, 0);
            #pragma unroll
            for (int ct = 0; ct < 2; ct++) {
                int o = ct * 16 + lrow;
                bf16x8 bv = *(const bf16x8*)(Vs + o * 256 + ((c0 ^ (o & 7)) << 3));
                oacc[ct] = __builtin_amdgcn_mfma_f32_16x16x32_bf16(ap, bv, oacc[ct], 0, 0, 0);
            }
        }

        // ---- 1/sum + gate multiply + store gated output [m,i,h,c]
        float rinv[4];
        #pragma unroll
        for (int r = 0; r < 4; r++)
            rinv[r] = __builtin_amdgcn_rcpf(osum[r]);
        #pragma unroll
        for (int ct = 0; ct < 2; ct++)
            #pragma unroll
            for (int r = 0; r < 4; r++) {
                int i = i0 + quad * 4 + r;
                float gv = bf2f(gv4[ct][r]);
                tm[i * 256 + ct * 16 + lrow] = f2bf(oacc[ct][r] * rinv[r] * gv);
            }
    }
}

// ---------------------------------------------------------------- final projection
// tmp [32768][256] @ WfT + bfinal -> out FP32.  grid (256, 2).
__global__ __launch_bounds__(256) void k_final(const u16* __restrict__ T, const u16* __restrict__ WfT,
                                               const float* __restrict__ bfinal, float* __restrict__ out) {
    __shared__ u16 As[128 * 64];
    __shared__ u16 Bs[128 * 64];
    int lane = threadIdx.x & 63, wave = threadIdx.x >> 6;
    int rowbase = blockIdx.x * 128;
    int colbase = blockIdx.y * 128;
    f32x4 acc[4][4];
    #pragma unroll
    for (int i = 0; i < 4; i++)
        #pragma unroll
        for (int j = 0; j < 4; j++)
            acc[i][j] = (f32x4){0.f, 0.f, 0.f, 0.f};
    gemm128_core(T, WfT, rowbase, colbase, 256, As, Bs, acc, lane, wave);
    int lrow = lane & 15, quad = lane >> 4;
    int wrb = rowbase + (wave >> 1) * 64, wcb = colbase + (wave & 1) * 64;
    #pragma unroll
    for (int it = 0; it < 4; it++)
        #pragma unroll
        for (int jt = 0; jt < 4; jt++)
            #pragma unroll
            for (int r = 0; r < 4; r++) {
                int grow = wrb + it * 16 + quad * 4 + r;
                int gcol = wcb + jt * 16 + lrow;
                out[grow * 256 + gcol] = acc[it][jt][r] + bfinal[gcol];
            }
}

// ---------------------------------------------------------------- launch
extern "C" void kernel_launch(void* const* d_in, const int* in_sizes, int n_in,
                              void* d_out, int out_size, void* d_ws, size_t ws_size,
                              hipStream_t stream) {
    const float* x1d   = (const float*)d_in[0];
    const float* x2d   = (const float*)d_in[1];
    const float* ln1_g = (const float*)d_in[2];
    const float* ln1_b = (const float*)d_in[3];
    const float* ln2_g = (const float*)d_in[4];
    const float* ln2_b = (const float*)d_in[5];
    const float* Wq    = (const float*)d_in[6];
    const float* Wk    = (const float*)d_in[7];
    const float* Wv    = (const float*)d_in[8];
    const float* W2d   = (const float*)d_in[9];
    const float* Wg    = (const float*)d_in[10];
    const float* bg    = (const float*)d_in[11];
    const float* Wf    = (const float*)d_in[12];
    const float* bfin  = (const float*)d_in[13];
    float* out = (float*)d_out;

    char* ws = (char*)d_ws;
    u16*   x1   = (u16*)(ws);                    // 16,777,216 B  (reused as tmp)
    u16*   WT   = (u16*)(ws + 16777216);         //    524,288 B
    u16*   WfT  = (u16*)(ws + 17301504);         //    131,072 B
    float* bias = (float*)(ws + 17432576);       //  2,097,152 B  (biasT[h][j][i], log2e-scaled)
    u16*   qb   = (u16*)(ws + 19529728);         // 16,777,216 B
    u16*   kb   = (u16*)(ws + 36306944);         // 16,777,216 B
    u16*   vtb  = (u16*)(ws + 53084160);         // 16,777,216 B
    u16*   gb   = (u16*)(ws + 69861376);         // 16,777,216 B  (end: 86,638,592)
    u16*   tmp  = x1;                            // x1 dead after k_qkvg

    k_transpose<<<1280, 256, 0, stream>>>(Wq, Wk, Wv, Wg, Wf, WT, WfT);
    k_ln1<<<8192, 256, 0, stream>>>(x1d, ln1_g, ln1_b, x1);
    k_ln2bias<<<16384, 256, 0, stream>>>(x2d, ln2_g, ln2_b, W2d, bias);
    k_qkvg<<<dim3(256, 8), 256, 0, stream>>>(x1, WT, qb, kb, vtb, gb, bg);
    k_attn<<<dim3(128, 8), 256, 0, stream>>>(qb, kb, vtb, gb, bias, tmp);
    k_final<<<dim3(256, 2), 256, 0, stream>>>(tmp, WfT, bfin, out);
}